// Round 6
// baseline (236.487 us; speedup 1.0000x reference)
//
#include <hip/hip_runtime.h>
#include <stdint.h>

// Conv2DUF: 3x3 s1 p1 conv, x[32][128][56][56] f32, weight[1152][256] f32
// (k = c*9 + kh*3 + kw), bias[256] f32 -> out[32][256][56][56] f32.
// bf16 implicit GEMM: M = 32*56*56 = 100352, N = 256, K = 1152.
//  ws: xt = bf16 x, GROUPED layout [c8grp(16)][B][58][58][8]  (halo = 0)
//      wt = bf16 weight reordered  [9][256][128]              (K-contiguous)
// R8: back to the best-measured base (R2: 128x256 tile, BK=64, 4 waves,
//     48KB LDS single-buffer, 2-barrier loop, multi-block/CU) with ONE change:
//     MFMA shape 16x16x32 -> 32x32x16 (ubench 2382 vs 2075 TF, 2x FLOP/inst,
//     half the issue slots). Wave tile 64x128 = 2x4 tiles of 32x32.
//     Same k-granule geometry (8 contig k / 16B), same slot^(row&7) swizzle.
//     + bijective XCD swizzle (784 = 8*98).

#define C_INQ 128
#define C_OUTQ 256
#define HDIM 56
#define WDIM 56
#define BDIM 32
#define HP 58
#define WP 58
#define HWPIX (HDIM * WDIM)                         // 3136
#define GSTRIDE (BDIM * HP * WP * 8)                // 861184 ushorts per c8-group
#define XT_ELEMS ((size_t)16 * GSTRIDE)             // 13,778,944
#define XT_BYTES (XT_ELEMS * 2)                     // 27,557,888

typedef __bf16 bf16x8 __attribute__((ext_vector_type(8)));
typedef unsigned short ushort8 __attribute__((ext_vector_type(8)));
typedef float floatx4 __attribute__((ext_vector_type(4)));
typedef float floatx16 __attribute__((ext_vector_type(16)));

__device__ __forceinline__ unsigned short f2bf(float f) {
  union { float f; unsigned int u; } v; v.f = f;
  unsigned int u = v.u;
  unsigned int r = u + 0x7FFFu + ((u >> 16) & 1u);   // RNE (finite inputs)
  return (unsigned short)(r >> 16);
}
__device__ __forceinline__ unsigned int pack2(float a, float b) {
  return (unsigned int)f2bf(a) | ((unsigned int)f2bf(b) << 16);
}

// ---------------- kernel 1 (fused prep):
//   blocks [0, 1856):     x NCHW f32 -> xt [g][B][58][58][8] bf16, zero halo
//   blocks [1856, 2000):  weight [1152][256] f32 -> wt [9][256][128] bf16
#define PAD_BLOCKS (BDIM * HP)      // 1856
__global__ __launch_bounds__(256) void prep_kernel(
    const float* __restrict__ x, unsigned short* __restrict__ xt,
    const float* __restrict__ w, unsigned short* __restrict__ wt) {
  const int t = threadIdx.x;
  if (blockIdx.x < PAD_BLOCKS) {
    const int blk = blockIdx.x;
    const int b = blk / HP;
    const int hp = blk - b * HP;
    uint4* __restrict__ xt4 = (uint4*)xt;  // one uint4 = 8 channels of a pixel
    if (hp == 0 || hp == HP - 1) {         // top/bottom halo rows
      for (int i = t; i < 16 * WP; i += 256) {
        int g = i / WP, wp = i - g * WP;
        xt4[((size_t)(g * BDIM + b) * HP + hp) * WP + wp] = make_uint4(0, 0, 0, 0);
      }
      return;
    }
    const int h = hp - 1;
    if (t < 224) {                         // 16 groups x 14 float4 along w
      const int g = t / 14;
      const int w4 = (t - g * 14) * 4;     // 0..52
      const float* xp = x + ((size_t)b * C_INQ + g * 8) * HWPIX + h * WDIM + w4;
      float4 L0 = *(const float4*)(xp);
      float4 L1 = *(const float4*)(xp + HWPIX);
      float4 L2 = *(const float4*)(xp + 2 * HWPIX);
      float4 L3 = *(const float4*)(xp + 3 * HWPIX);
      float4 L4 = *(const float4*)(xp + 4 * HWPIX);
      float4 L5 = *(const float4*)(xp + 5 * HWPIX);
      float4 L6 = *(const float4*)(xp + 6 * HWPIX);
      float4 L7 = *(const float4*)(xp + 7 * HWPIX);
      uint4* dst = xt4 + ((size_t)(g * BDIM + b) * HP + hp) * WP + 1 + w4;
      dst[0] = make_uint4(pack2(L0.x, L1.x), pack2(L2.x, L3.x),
                          pack2(L4.x, L5.x), pack2(L6.x, L7.x));
      dst[1] = make_uint4(pack2(L0.y, L1.y), pack2(L2.y, L3.y),
                          pack2(L4.y, L5.y), pack2(L6.y, L7.y));
      dst[2] = make_uint4(pack2(L0.z, L1.z), pack2(L2.z, L3.z),
                          pack2(L4.z, L5.z), pack2(L6.z, L7.z));
      dst[3] = make_uint4(pack2(L0.w, L1.w), pack2(L2.w, L3.w),
                          pack2(L4.w, L5.w), pack2(L6.w, L7.w));
    } else {                               // 32 spare threads: left/right halo
      const int r = t - 224;
      const int g = r >> 1;
      const int wp = (r & 1) * (WP - 1);
      xt4[((size_t)(g * BDIM + b) * HP + hp) * WP + wp] = make_uint4(0, 0, 0, 0);
    }
  } else {
    const int bx = blockIdx.x - PAD_BLOCKS;  // 0..143
    const int khw = bx >> 4;
    const int r4 = bx & 15;
    const int n0w = (r4 >> 2) * 64;
    const int c32 = (r4 & 3) * 32;
    __shared__ float lds[32 * 66];           // [c][n], stride 66
#pragma unroll
    for (int r = 0; r < 8; ++r) {
      int idx = r * 256 + t;                 // 32*64 = 2048
      int n = idx & 63, c = idx >> 6;
      lds[c * 66 + n] = w[(size_t)((c32 + c) * 9 + khw) * C_OUTQ + n0w + n];
    }
    __syncthreads();
    {
      int n = t >> 2, c8 = (t & 3) * 8;
      const float* s = lds + c8 * 66 + n;
      uint4 o;
      o.x = pack2(s[0],   s[66]);
      o.y = pack2(s[132], s[198]);
      o.z = pack2(s[264], s[330]);
      o.w = pack2(s[396], s[462]);
      *(uint4*)(wt + (size_t)khw * (C_OUTQ * C_INQ) + (size_t)(n0w + n) * C_INQ + c32 + c8) = o;
    }
  }
}

// ---------------- kernel 2: implicit GEMM, 128x256 tile, BK=64, 4 waves,
// mfma_f32_32x32x16_bf16. Wave tile 64x128 = 2m x 4n tiles of 32x32.
// Single-buffer LDS (48KB), R2's 2-barrier loop (best measured base).
#define BM 128
#define BN 256
#define BK 64
#define STEPS 18

__global__ __launch_bounds__(256, 2) void conv_gemm_kernel(
    const unsigned short* __restrict__ xt,
    const unsigned short* __restrict__ wt,
    const float* __restrict__ bias,
    float* __restrict__ out) {
  // granule = 16B (8 ush). data(row,kgran) at slot kgran^(row&7) within row.
  __shared__ __align__(16) unsigned short ldsA[BM * BK];  // 16KB
  __shared__ __align__(16) unsigned short ldsB[BN * BK];  // 32KB

  const int t = threadIdx.x;
  const int lane = t & 63;
  const int wave = t >> 6;
  // bijective XCD swizzle (784 = 8*98): XCD k owns tiles [k*98,(k+1)*98)
  const int tile_m = ((int)blockIdx.x & 7) * 98 + ((int)blockIdx.x >> 3);

  // staging: A rounds 0..3, B rounds 0..7; round r stages granule g = r*256+t
  int gbaseA[4], gbaseB[8];
#pragma unroll
  for (int r = 0; r < 4; ++r) {
    int g = r * 256 + t;
    int row = g >> 3;
    int kp = (g & 7) ^ (row & 7);          // swizzle inverse (pre-swizzled src)
    int pix = tile_m * BM + row;
    int b = pix / HWPIX;
    int p = pix - b * HWPIX;
    int h = p / WDIM;
    int w = p - h * WDIM;
    gbaseA[r] = kp * GSTRIDE + ((b * HP + h) * WP + w) * 8;
  }
#pragma unroll
  for (int r = 0; r < 8; ++r) {
    int g = r * 256 + t;
    int row = g >> 3;                      // = n (BN == C_OUTQ)
    int kp = (g & 7) ^ (row & 7);
    gbaseB[r] = row * C_INQ + kp * 8;
  }

  // fragment geometry: wave grid 2x2 -> wave tile 64m x 128n = 2x4 32x32 tiles
  const int wm = (wave >> 1) * 64;
  const int wn = (wave & 1) * 128;
  const int l31 = lane & 31;
  const int khalf = lane >> 5;             // k-granule half within each ksub

  int arow[2], brow[4], sk[4];
#pragma unroll
  for (int mt = 0; mt < 2; ++mt) arow[mt] = (wm + mt * 32 + l31) * BK;
#pragma unroll
  for (int nt = 0; nt < 4; ++nt) brow[nt] = (wn + nt * 32 + l31) * BK;
#pragma unroll
  for (int ks = 0; ks < 4; ++ks) sk[ks] = ((2 * ks + khalf) ^ (l31 & 7)) * 8;

  floatx16 acc[2][4] = {};

#define BC8(p) __builtin_bit_cast(bf16x8, *(const ushort8*)(p))

#pragma unroll 1
  for (int s = 0; s < STEPS; ++s) {
    const int khw = s >> 1;
    const int ch = s & 1;
    const int kh = khw / 3;
    const int kw = khw - kh * 3;
    const int koffA = ch * 8 * GSTRIDE + (kh * WP + kw) * 8;   // wave-uniform
    const int koffB = khw * (C_OUTQ * C_INQ) + ch * 64;
#pragma unroll
    for (int r = 0; r < 4; ++r)
      __builtin_amdgcn_global_load_lds(
          (const __attribute__((address_space(1))) unsigned int*)(xt + gbaseA[r] + koffA),
          (__attribute__((address_space(3))) unsigned int*)(ldsA + (r * 256 + wave * 64) * 8),
          16, 0, 0);
#pragma unroll
    for (int r = 0; r < 8; ++r)
      __builtin_amdgcn_global_load_lds(
          (const __attribute__((address_space(1))) unsigned int*)(wt + gbaseB[r] + koffB),
          (__attribute__((address_space(3))) unsigned int*)(ldsB + (r * 256 + wave * 64) * 8),
          16, 0, 0);
    __syncthreads();   // drains vmcnt -> LDS tiles valid

#pragma unroll
    for (int ks = 0; ks < 4; ++ks) {
      bf16x8 a0 = BC8(ldsA + arow[0] + sk[ks]);
      bf16x8 a1 = BC8(ldsA + arow[1] + sk[ks]);
#pragma unroll
      for (int nt = 0; nt < 4; ++nt) {
        bf16x8 bfr = BC8(ldsB + brow[nt] + sk[ks]);
        acc[0][nt] = __builtin_amdgcn_mfma_f32_32x32x16_bf16(a0, bfr, acc[0][nt], 0, 0, 0);
        acc[1][nt] = __builtin_amdgcn_mfma_f32_32x32x16_bf16(a1, bfr, acc[1][nt], 0, 0, 0);
      }
    }
    __syncthreads();   // protect LDS before next step's staging
  }
#undef BC8

  // epilogue: 32x32 C/D layout: col(n) = lane&31,
  // row(m) = (reg&3) + 8*(reg>>2) + 4*(lane>>5). Reg groups of 4 = 4
  // consecutive m-pixels -> one float4 store (3136 % 4 == 0, bases %4 == 0).
  float bv[4];
#pragma unroll
  for (int nt = 0; nt < 4; ++nt) bv[nt] = bias[wn + nt * 32 + l31];
#pragma unroll
  for (int mt = 0; mt < 2; ++mt) {
#pragma unroll
    for (int g = 0; g < 4; ++g) {
      const int mbase = tile_m * BM + wm + mt * 32 + g * 8 + khalf * 4;
      const int b = mbase / HWPIX;
      const int p = mbase - b * HWPIX;
      float* obase = out + (size_t)b * (C_OUTQ * HWPIX) + p;
#pragma unroll
      for (int nt = 0; nt < 4; ++nt) {
        const int n = wn + nt * 32 + l31;
        floatx4 v;
        v[0] = acc[mt][nt][g * 4 + 0] + bv[nt];
        v[1] = acc[mt][nt][g * 4 + 1] + bv[nt];
        v[2] = acc[mt][nt][g * 4 + 2] + bv[nt];
        v[3] = acc[mt][nt][g * 4 + 3] + bv[nt];
        *(floatx4*)(obase + (size_t)n * HWPIX) = v;
      }
    }
  }
}

extern "C" void kernel_launch(void* const* d_in, const int* in_sizes, int n_in,
                              void* d_out, int out_size, void* d_ws, size_t ws_size,
                              hipStream_t stream) {
  const float* x    = (const float*)d_in[0];
  const float* w    = (const float*)d_in[1];
  const float* bias = (const float*)d_in[2];
  float* out = (float*)d_out;

  unsigned short* xt = (unsigned short*)d_ws;
  unsigned short* wt = (unsigned short*)((char*)d_ws + XT_BYTES);  // +589,824 B

  hipLaunchKernelGGL(prep_kernel, dim3(PAD_BLOCKS + 144), dim3(256), 0, stream,
                     x, xt, w, wt);
  hipLaunchKernelGGL(conv_gemm_kernel, dim3(784), dim3(256), 0, stream,
                     xt, wt, bias, out);
}

// Round 7
// 228.358 us; speedup vs baseline: 1.0356x; 1.0356x over previous
//
#include <hip/hip_runtime.h>
#include <stdint.h>

// Conv2DUF: 3x3 s1 p1 conv, x[32][128][56][56] f32, weight[1152][256] f32
// (k = c*9 + kh*3 + kw), bias[256] f32 -> out[32][256][56][56] f32.
// bf16 implicit GEMM: M = 32*56*56 = 100352, N = 256, K = 1152.
//  ws: xt = bf16 x, GROUPED layout [c8grp(16)][B][58][58][8]  (halo = 0)
//      wt = bf16 weight reordered  [9][256][128]              (K-contiguous)
// R9: R2's proven base (128x256, 16x16x32, 4 waves, multi-block/CU) +
//     ping-pong BK=32 double-buffer (48KB total, same residency as R2) +
//     counted vmcnt(6) (loads never drain to 0 in main loop; one K-step of
//     flight time) + CORRECTED BK=32 swizzle slot = quad^((row>>1)&3)
//     (column class (4r+s) mod 8 covers all 8 classes 2x over 16 lanes ->
//     2-way = free; R3's row&3 variant was 4-way = its 5.4M conflicts).

#define C_INQ 128
#define C_OUTQ 256
#define HDIM 56
#define WDIM 56
#define BDIM 32
#define HP 58
#define WP 58
#define HWPIX (HDIM * WDIM)                         // 3136
#define GSTRIDE (BDIM * HP * WP * 8)                // 861184 ushorts per c8-group
#define XT_ELEMS ((size_t)16 * GSTRIDE)             // 13,778,944
#define XT_BYTES (XT_ELEMS * 2)                     // 27,557,888

typedef __bf16 bf16x8 __attribute__((ext_vector_type(8)));
typedef unsigned short ushort8 __attribute__((ext_vector_type(8)));
typedef float floatx4 __attribute__((ext_vector_type(4)));

__device__ __forceinline__ unsigned short f2bf(float f) {
  union { float f; unsigned int u; } v; v.f = f;
  unsigned int u = v.u;
  unsigned int r = u + 0x7FFFu + ((u >> 16) & 1u);   // RNE (finite inputs)
  return (unsigned short)(r >> 16);
}
__device__ __forceinline__ unsigned int pack2(float a, float b) {
  return (unsigned int)f2bf(a) | ((unsigned int)f2bf(b) << 16);
}

// ---------------- kernel 1 (fused prep):
//   blocks [0, 1856):     x NCHW f32 -> xt [g][B][58][58][8] bf16, zero halo
//   blocks [1856, 2000):  weight [1152][256] f32 -> wt [9][256][128] bf16
#define PAD_BLOCKS (BDIM * HP)      // 1856
__global__ __launch_bounds__(256) void prep_kernel(
    const float* __restrict__ x, unsigned short* __restrict__ xt,
    const float* __restrict__ w, unsigned short* __restrict__ wt) {
  const int t = threadIdx.x;
  if (blockIdx.x < PAD_BLOCKS) {
    const int blk = blockIdx.x;
    const int b = blk / HP;
    const int hp = blk - b * HP;
    uint4* __restrict__ xt4 = (uint4*)xt;  // one uint4 = 8 channels of a pixel
    if (hp == 0 || hp == HP - 1) {         // top/bottom halo rows
      for (int i = t; i < 16 * WP; i += 256) {
        int g = i / WP, wp = i - g * WP;
        xt4[((size_t)(g * BDIM + b) * HP + hp) * WP + wp] = make_uint4(0, 0, 0, 0);
      }
      return;
    }
    const int h = hp - 1;
    if (t < 224) {                         // 16 groups x 14 float4 along w
      const int g = t / 14;
      const int w4 = (t - g * 14) * 4;     // 0..52
      const float* xp = x + ((size_t)b * C_INQ + g * 8) * HWPIX + h * WDIM + w4;
      float4 L0 = *(const float4*)(xp);
      float4 L1 = *(const float4*)(xp + HWPIX);
      float4 L2 = *(const float4*)(xp + 2 * HWPIX);
      float4 L3 = *(const float4*)(xp + 3 * HWPIX);
      float4 L4 = *(const float4*)(xp + 4 * HWPIX);
      float4 L5 = *(const float4*)(xp + 5 * HWPIX);
      float4 L6 = *(const float4*)(xp + 6 * HWPIX);
      float4 L7 = *(const float4*)(xp + 7 * HWPIX);
      uint4* dst = xt4 + ((size_t)(g * BDIM + b) * HP + hp) * WP + 1 + w4;
      dst[0] = make_uint4(pack2(L0.x, L1.x), pack2(L2.x, L3.x),
                          pack2(L4.x, L5.x), pack2(L6.x, L7.x));
      dst[1] = make_uint4(pack2(L0.y, L1.y), pack2(L2.y, L3.y),
                          pack2(L4.y, L5.y), pack2(L6.y, L7.y));
      dst[2] = make_uint4(pack2(L0.z, L1.z), pack2(L2.z, L3.z),
                          pack2(L4.z, L5.z), pack2(L6.z, L7.z));
      dst[3] = make_uint4(pack2(L0.w, L1.w), pack2(L2.w, L3.w),
                          pack2(L4.w, L5.w), pack2(L6.w, L7.w));
    } else {                               // 32 spare threads: left/right halo
      const int r = t - 224;
      const int g = r >> 1;
      const int wp = (r & 1) * (WP - 1);
      xt4[((size_t)(g * BDIM + b) * HP + hp) * WP + wp] = make_uint4(0, 0, 0, 0);
    }
  } else {
    const int bx = blockIdx.x - PAD_BLOCKS;  // 0..143
    const int khw = bx >> 4;
    const int r4 = bx & 15;
    const int n0w = (r4 >> 2) * 64;
    const int c32 = (r4 & 3) * 32;
    __shared__ float lds[32 * 66];           // [c][n], stride 66
#pragma unroll
    for (int r = 0; r < 8; ++r) {
      int idx = r * 256 + t;                 // 32*64 = 2048
      int n = idx & 63, c = idx >> 6;
      lds[c * 66 + n] = w[(size_t)((c32 + c) * 9 + khw) * C_OUTQ + n0w + n];
    }
    __syncthreads();
    {
      int n = t >> 2, c8 = (t & 3) * 8;
      const float* s = lds + c8 * 66 + n;
      uint4 o;
      o.x = pack2(s[0],   s[66]);
      o.y = pack2(s[132], s[198]);
      o.z = pack2(s[264], s[330]);
      o.w = pack2(s[396], s[462]);
      *(uint4*)(wt + (size_t)khw * (C_OUTQ * C_INQ) + (size_t)(n0w + n) * C_INQ + c32 + c8) = o;
    }
  }
}

// ---------------- kernel 2: implicit GEMM, 128x256 tile, BK=32 ping-pong,
// 4 waves, 16x16x32 MFMA, counted vmcnt(6). LDS 48KB (= R2's residency).
#define BM 128
#define BN 256
#define BK 32
#define NSTEP 36                          // kt = khw*4 + cq (cq = 32-ch quarter)
#define ABUF 4096                         // ushorts per A buffer (128*32)
#define BBUF 8192                         // ushorts per B buffer (256*32)

__global__ __launch_bounds__(256, 2) void conv_gemm_kernel(
    const unsigned short* __restrict__ xt,
    const unsigned short* __restrict__ wt,
    const float* __restrict__ bias,
    float* __restrict__ out) {
  // granule = 16B (8 ush); 4 granules/row. data(row,kgran) stored at slot
  // kgran ^ ((row>>1)&3)  ->  2-way max on both staging and fragment reads.
  __shared__ __align__(16) unsigned short ldsA[2 * ABUF];  // 16KB
  __shared__ __align__(16) unsigned short ldsB[2 * BBUF];  // 32KB

  const int t = threadIdx.x;
  const int lane = t & 63;
  const int wave = t >> 6;
  // bijective XCD swizzle (784 = 8*98): XCD k owns tiles [k*98,(k+1)*98)
  const int tile_m = ((int)blockIdx.x & 7) * 98 + ((int)blockIdx.x >> 3);

  // staging: A rounds 0..1, B rounds 0..3; round r stages granule g = r*256+t
  int gbaseA[2], gbaseB[4];
#pragma unroll
  for (int r = 0; r < 2; ++r) {
    int g = r * 256 + t;
    int row = g >> 2;                      // 0..127
    int kg = (g & 3) ^ ((row >> 1) & 3);   // swizzle inverse
    int pix = tile_m * BM + row;
    int b = pix / HWPIX;
    int p = pix - b * HWPIX;
    int h = p / WDIM;
    int w = p - h * WDIM;
    gbaseA[r] = kg * GSTRIDE + ((b * HP + h) * WP + w) * 8;
  }
#pragma unroll
  for (int r = 0; r < 4; ++r) {
    int g = r * 256 + t;
    int row = g >> 2;                      // = n (BN == C_OUTQ)
    int kg = (g & 3) ^ ((row >> 1) & 3);
    gbaseB[r] = row * C_INQ + kg * 8;
  }

  // fragment geometry: wave grid 2x2 -> wave tile 64m x 128n
  const int wm = (wave >> 1) * 64;
  const int wn = (wave & 1) * 128;
  const int mrow = lane & 15;
  const int quad = lane >> 4;              // kgran of this lane's 8-k chunk

  int aoff[4], boff[8];                    // ush offsets within a buffer
#pragma unroll
  for (int i = 0; i < 4; ++i) {
    int r = wm + i * 16 + mrow;
    aoff[i] = r * BK + ((quad ^ ((r >> 1) & 3)) * 8);
  }
#pragma unroll
  for (int j = 0; j < 8; ++j) {
    int n = wn + j * 16 + mrow;
    boff[j] = n * BK + ((quad ^ ((n >> 1) & 3)) * 8);
  }

  floatx4 acc[4][8] = {};

  // stage K-step kt into buffer buf: 2 A + 4 B global_load_lds per thread
  auto stage = [&](int kt, int buf) {
    const int khw = kt >> 2, cq = kt & 3;
    const int kh = khw / 3, kw = khw - kh * 3;
    const int koffA = cq * 4 * GSTRIDE + (kh * WP + kw) * 8;
    const int koffB = khw * (C_OUTQ * C_INQ) + cq * 32;
#pragma unroll
    for (int r = 0; r < 2; ++r)
      __builtin_amdgcn_global_load_lds(
          (const __attribute__((address_space(1))) unsigned int*)(xt + gbaseA[r] + koffA),
          (__attribute__((address_space(3))) unsigned int*)(ldsA + buf * ABUF + (r * 256 + t) * 8),
          16, 0, 0);
#pragma unroll
    for (int r = 0; r < 4; ++r)
      __builtin_amdgcn_global_load_lds(
          (const __attribute__((address_space(1))) unsigned int*)(wt + gbaseB[r] + koffB),
          (__attribute__((address_space(3))) unsigned int*)(ldsB + buf * BBUF + (r * 256 + t) * 8),
          16, 0, 0);
  };

#define BC8(p) __builtin_bit_cast(bf16x8, *(const ushort8*)(p))

  auto compute = [&](int buf) {            // 12 ds_read_b128 + 32 MFMA
    const unsigned short* A = ldsA + buf * ABUF;
    const unsigned short* B = ldsB + buf * BBUF;
    bf16x8 afr[4], bfr[8];
#pragma unroll
    for (int i = 0; i < 4; ++i) afr[i] = BC8(A + aoff[i]);
#pragma unroll
    for (int j = 0; j < 8; ++j) bfr[j] = BC8(B + boff[j]);
    __builtin_amdgcn_s_setprio(1);
#pragma unroll
    for (int i = 0; i < 4; ++i)
#pragma unroll
      for (int j = 0; j < 8; ++j)
        acc[i][j] = __builtin_amdgcn_mfma_f32_16x16x32_bf16(afr[i], bfr[j], acc[i][j], 0, 0, 0);
    __builtin_amdgcn_s_setprio(0);
  };

  // K_STEP: counted wait (stage(kt) landed, stage(kt+1)'s 6 loads in flight),
  // barrier (all waves' portions valid), compute, barrier (reads done),
  // restage this buffer with kt+2.
#define K_STEP(KT, BUF, VM, DOSTAGE)                                 \
  {                                                                  \
    asm volatile("s_waitcnt vmcnt(" VM ")" ::: "memory");            \
    __builtin_amdgcn_s_barrier();                                    \
    compute(BUF);                                                    \
    __builtin_amdgcn_s_barrier();                                    \
    if (DOSTAGE) stage((KT) + 2, BUF);                               \
  }

  stage(0, 0);
  stage(1, 1);                             // 12 outstanding per thread

#pragma unroll 1
  for (int so = 0; so < 17; ++so) {        // kt 0..33: keep 6 in flight
    K_STEP(so * 2, 0, "6", true);
    K_STEP(so * 2 + 1, 1, "6", true);
  }
  K_STEP(34, 0, "6", false);               // stage(35) stays in flight
  K_STEP(35, 1, "0", false);               // drain
#undef K_STEP
#undef BC8

  // epilogue: C/D layout col(n) = lane&15, row(m) = quad*4 + reg.
  // 4 consecutive pixels per lane -> one float4 store (3136 % 4 == 0).
  float bv[8];
#pragma unroll
  for (int jn = 0; jn < 8; ++jn) bv[jn] = bias[wn + jn * 16 + mrow];
#pragma unroll
  for (int i = 0; i < 4; ++i) {
    const int mbase = tile_m * BM + wm + i * 16 + quad * 4;
    const int b = mbase / HWPIX;
    const int p = mbase - b * HWPIX;
    float* obase = out + (size_t)b * (C_OUTQ * HWPIX) + p;
#pragma unroll
    for (int jn = 0; jn < 8; ++jn) {
      const int ng = wn + jn * 16 + mrow;
      floatx4 v = acc[i][jn];
      v[0] += bv[jn]; v[1] += bv[jn]; v[2] += bv[jn]; v[3] += bv[jn];
      *(floatx4*)(obase + (size_t)ng * HWPIX) = v;
    }
  }
}

extern "C" void kernel_launch(void* const* d_in, const int* in_sizes, int n_in,
                              void* d_out, int out_size, void* d_ws, size_t ws_size,
                              hipStream_t stream) {
  const float* x    = (const float*)d_in[0];
  const float* w    = (const float*)d_in[1];
  const float* bias = (const float*)d_in[2];
  float* out = (float*)d_out;

  unsigned short* xt = (unsigned short*)d_ws;
  unsigned short* wt = (unsigned short*)((char*)d_ws + XT_BYTES);  // +589,824 B

  hipLaunchKernelGGL(prep_kernel, dim3(PAD_BLOCKS + 144), dim3(256), 0, stream,
                     x, xt, w, wt);
  hipLaunchKernelGGL(conv_gemm_kernel, dim3(784), dim3(256), 0, stream,
                     xt, wt, bias, out);
}